// Round 2
// baseline (6921.797 us; speedup 1.0000x reference)
//
#include <hip/hip_runtime.h>
#include <hip/hip_fp16.h>

typedef _Float16 f16;
typedef __attribute__((ext_vector_type(8))) _Float16 f16x8;
typedef __attribute__((ext_vector_type(4))) float f32x4;

#define SWZ(r) ((((r)&3) ^ (((r)>>2)&3)))

// ---------------------------------------------------------------------------
// 128x128 tile GEMM core: C[128 m x 128 n] = A[128 x K] * B(rows)[128 x K]^T
// A row-major (lda). B row-major (ldb); B tile row rb -> global row
//   nbase + (rb>>5)*strideG + ((rb>>4)&1)*16 + (rb&15)
// (strideG=2048: 4 gates x 32-hid blocks; strideG=32: contiguous 128 rows).
// 4 waves in 2x2: wave w -> mhalf=w&1 (64 m-rows), hhalf=w>>1 (16-col halves).
// acc[mt][nt]: m = mhalf*64 + mt*16 + quad*4 + reg, n-tile nt (16 cols:
// rb = nt*32 + hhalf*16 + l15). Staging: global_load_lds 16B chunks,
// XOR-swizzled so fragment ds_read_b128 hits the right k-quad.
// ---------------------------------------------------------------------------
__device__ __forceinline__ void gemm128(
    const f16* __restrict__ A, int lda,
    const f16* __restrict__ Bm, int ldb,
    int K, int bm0, int nbase, int strideG,
    f16* As, f16* Bs, f32x4 acc[4][4])
{
    const int tid  = threadIdx.x;
    const int wave = tid >> 6;
    const int lane = tid & 63;
    const int l15  = lane & 15;
    const int quad = lane >> 4;
    const int mhalf = wave & 1, hhalf = wave >> 1;

    #pragma unroll
    for (int mt = 0; mt < 4; ++mt)
      #pragma unroll
      for (int nt = 0; nt < 4; ++nt)
        acc[mt][nt] = (f32x4){0.f, 0.f, 0.f, 0.f};

    // A and B are each 128 rows x 32 k = 512 16B-chunks -> 2 rounds of 256.
    const int c0 = tid, c1 = tid + 256;
    const int r0 = c0 >> 2, r1 = c1 >> 2;
    const int kq0 = (c0 & 3) ^ SWZ(r0);
    const int kq1 = (c1 & 3) ^ SWZ(r1);
    const f16* gA0 = A + (size_t)(bm0 + r0) * lda + kq0 * 8;
    const f16* gA1 = A + (size_t)(bm0 + r1) * lda + kq1 * 8;
    const int br0 = nbase + (r0 >> 5) * strideG + ((r0 >> 4) & 1) * 16 + (r0 & 15);
    const int br1 = nbase + (r1 >> 5) * strideG + ((r1 >> 4) & 1) * 16 + (r1 & 15);
    const f16* gB0 = Bm + (size_t)br0 * ldb + kq0 * 8;
    const f16* gB1 = Bm + (size_t)br1 * ldb + kq1 * 8;

    // wave-uniform LDS destinations (HW: base + lane*16)
    f16* ldsA0 = As + wave * 512;
    f16* ldsA1 = As + 2048 + wave * 512;
    f16* ldsB0 = Bs + wave * 512;
    f16* ldsB1 = Bs + 2048 + wave * 512;

    // fragment LDS element offsets (chunk slot = row*4 + (quad ^ SWZ(row)))
    int offA[4], offB[4];
    const int sw = SWZ(l15);
    #pragma unroll
    for (int mt = 0; mt < 4; ++mt) {
        int r = mhalf * 64 + mt * 16 + l15;
        offA[mt] = (r * 4 + (quad ^ sw)) * 8;
    }
    #pragma unroll
    for (int nt = 0; nt < 4; ++nt) {
        int r = nt * 32 + hhalf * 16 + l15;
        offB[nt] = (r * 4 + (quad ^ sw)) * 8;
    }

    for (int k0 = 0; k0 < K; k0 += 32) {
        __builtin_amdgcn_global_load_lds(
            (const __attribute__((address_space(1))) void*)(gA0 + k0),
            (__attribute__((address_space(3))) void*)ldsA0, 16, 0, 0);
        __builtin_amdgcn_global_load_lds(
            (const __attribute__((address_space(1))) void*)(gA1 + k0),
            (__attribute__((address_space(3))) void*)ldsA1, 16, 0, 0);
        __builtin_amdgcn_global_load_lds(
            (const __attribute__((address_space(1))) void*)(gB0 + k0),
            (__attribute__((address_space(3))) void*)ldsB0, 16, 0, 0);
        __builtin_amdgcn_global_load_lds(
            (const __attribute__((address_space(1))) void*)(gB1 + k0),
            (__attribute__((address_space(3))) void*)ldsB1, 16, 0, 0);
        __syncthreads();
        f16x8 af[4], bf[4];
        #pragma unroll
        for (int mt = 0; mt < 4; ++mt) af[mt] = *(const f16x8*)(As + offA[mt]);
        #pragma unroll
        for (int nt = 0; nt < 4; ++nt) bf[nt] = *(const f16x8*)(Bs + offB[nt]);
        #pragma unroll
        for (int mt = 0; mt < 4; ++mt)
          #pragma unroll
          for (int nt = 0; nt < 4; ++nt)
            acc[mt][nt] = __builtin_amdgcn_mfma_f32_16x16x32_f16(
                af[mt], bf[nt], acc[mt][nt], 0, 0, 0);
        __syncthreads();
    }
}

// ---------------------------------------------------------------------------
// One recurrent step (also step 0 with A=x0,K=128,W=W_ih):
// gates = A @ W^T + bias ; cell ; write h (fp16) and c (fp32).
// Block: 128 batch x (32 hid x 4 gates); nt == gate, so the cell is in-lane.
// XCD swizzle: each XCD owns a fixed 1/8 of W' rows (4 MB ~= its L2).
// ---------------------------------------------------------------------------
__global__ __launch_bounds__(256, 1) void k_step(
    const f16* __restrict__ A, int lda, int K,
    const f16* __restrict__ W, int ldb,
    const float* __restrict__ bias,
    float* __restrict__ Cst,
    f16* __restrict__ Hout)
{
    __shared__ alignas(16) f16 As[4096];
    __shared__ alignas(16) f16 Bs[4096];
    const int blk = blockIdx.x;
    const int ng  = (blk & 7) * 8 + ((blk >> 3) & 7);  // 0..63, xcd-pinned
    const int bg  = blk >> 6;                           // 0..3
    const int hid0 = ng * 32;
    const int bm0  = bg * 128;
    f32x4 acc[4][4];
    gemm128(A, lda, W, ldb, K, bm0, hid0, 2048, As, Bs, acc);

    const int lane = threadIdx.x & 63;
    const int wave = threadIdx.x >> 6;
    const int l15 = lane & 15, quad = lane >> 4;
    const int mhalf = wave & 1, hhalf = wave >> 1;
    const int hid = hid0 + hhalf * 16 + l15;
    const float bI = bias[hid];
    const float bF = bias[2048 + hid];
    const float bG = bias[4096 + hid];
    const float bO = bias[6144 + hid];
    #pragma unroll
    for (int mt = 0; mt < 4; ++mt) {
      #pragma unroll
      for (int reg = 0; reg < 4; ++reg) {
        const int row = bm0 + mhalf * 64 + mt * 16 + quad * 4 + reg;
        const size_t idx = (size_t)row * 2048 + hid;
        float iv = acc[mt][0][reg] + bI;
        float fv = acc[mt][1][reg] + bF;
        float gv = acc[mt][2][reg] + bG;
        float ov = acc[mt][3][reg] + bO;
        float si = 1.f / (1.f + __expf(-iv));
        float sf = 1.f / (1.f + __expf(-fv));
        float so = 1.f / (1.f + __expf(-ov));
        float tg = tanhf(gv);
        float c = sf * Cst[idx] + si * tg;
        Cst[idx] = c;
        Hout[idx] = (f16)(so * tanhf(c));
      }
    }
}

// out[b, t, d] = H[slot, b, :] @ W_out[d, :] + b_out[d];  t = t0 + slot
__global__ __launch_bounds__(256, 1) void k_out(
    const f16* __restrict__ Hbase,
    const f16* __restrict__ Wout,
    const float* __restrict__ bout,
    float* __restrict__ out, int t0)
{
    __shared__ alignas(16) f16 As[4096];
    __shared__ alignas(16) f16 Bs[4096];
    const int bm0 = blockIdx.x * 128;  // over M = depth*512
    f32x4 acc[4][4];
    gemm128(Hbase, 2048, Wout, 2048, 2048, bm0, 0, 32, As, Bs, acc);
    const int lane = threadIdx.x & 63;
    const int wave = threadIdx.x >> 6;
    const int l15 = lane & 15, quad = lane >> 4;
    const int mhalf = wave & 1, hhalf = wave >> 1;
    #pragma unroll
    for (int nt = 0; nt < 4; ++nt) {
      const int d = nt * 32 + hhalf * 16 + l15;
      const float bo = bout[d];
      #pragma unroll
      for (int mt = 0; mt < 4; ++mt) {
        #pragma unroll
        for (int reg = 0; reg < 4; ++reg) {
          const int m = bm0 + mhalf * 64 + mt * 16 + quad * 4 + reg;
          const int slot = m >> 9, b = m & 511;
          const int t = t0 + slot;
          out[(size_t)b * 16384 + t * 128 + d] = acc[mt][nt][reg] + bo;
        }
      }
    }
}

// W'[r,k] = W_hh[r,k] + sum_d W_ih[r,d]*W_out[d,k], via f16 MFMA + fp32 add.
__global__ __launch_bounds__(256, 1) void k_wcomb2(
    const f16* __restrict__ Wih16, const f16* __restrict__ WoutT,
    const float* __restrict__ Whh, f16* __restrict__ Wc)
{
    __shared__ alignas(16) f16 As[4096];
    __shared__ alignas(16) f16 Bs[4096];
    const int n0  = blockIdx.x * 128;  // 16 blocks over 2048 cols
    const int bm0 = blockIdx.y * 128;  // 64 blocks over 8192 rows
    f32x4 acc[4][4];
    gemm128(Wih16, 128, WoutT, 128, 128, bm0, n0, 32, As, Bs, acc);
    const int lane = threadIdx.x & 63;
    const int wave = threadIdx.x >> 6;
    const int l15 = lane & 15, quad = lane >> 4;
    const int mhalf = wave & 1, hhalf = wave >> 1;
    #pragma unroll
    for (int nt = 0; nt < 4; ++nt) {
      const int col = n0 + nt * 32 + hhalf * 16 + l15;
      #pragma unroll
      for (int mt = 0; mt < 4; ++mt) {
        #pragma unroll
        for (int reg = 0; reg < 4; ++reg) {
          const int row = bm0 + mhalf * 64 + mt * 16 + quad * 4 + reg;
          const size_t idx = (size_t)row * 2048 + col;
          Wc[idx] = (f16)(acc[mt][nt][reg] + Whh[idx]);
        }
      }
    }
}

// ---------------- prep kernels (run once per launch) ------------------------

__global__ void k_cast(const float* __restrict__ s, f16* __restrict__ d, int n)
{
    int i = blockIdx.x * 256 + threadIdx.x;
    if (i < n) d[i] = (f16)s[i];
}

// WoutT[k,d] = Wout[d,k]  (fp32 [128 x 2048] -> f16 [2048 x 128])
__global__ __launch_bounds__(256) void k_tr(const float* __restrict__ Wout,
                                            f16* __restrict__ WoutT)
{
    __shared__ float T[64][65];
    const int k0 = blockIdx.x * 64;  // 32
    const int d0 = blockIdx.y * 64;  // 2
    const int t = threadIdx.x;
    const int r = t >> 2, cq = t & 3;
    #pragma unroll
    for (int j = 0; j < 4; ++j) {
        const float* p = Wout + (size_t)(d0 + r) * 2048 + k0 + cq * 16 + j * 4;
        T[r][cq * 16 + j * 4 + 0] = p[0];
        T[r][cq * 16 + j * 4 + 1] = p[1];
        T[r][cq * 16 + j * 4 + 2] = p[2];
        T[r][cq * 16 + j * 4 + 3] = p[3];
    }
    __syncthreads();
    f16 tmp[16];
    #pragma unroll
    for (int j = 0; j < 16; ++j) tmp[j] = (f16)T[cq * 16 + j][r];
    #pragma unroll
    for (int j = 0; j < 16; ++j)
        WoutT[(size_t)(k0 + r) * 128 + d0 + cq * 16 + j] = tmp[j];
}

__global__ void k_x0(const float* __restrict__ tgt, f16* __restrict__ x0)
{
    int i = blockIdx.x * 256 + threadIdx.x;  // 65536 total
    int b = i >> 7, d = i & 127;
    x0[i] = (f16)tgt[(size_t)b * 16384 + d];  // tgt[b, 0, d]
}

__global__ void k_bias(const float* __restrict__ bih, const float* __restrict__ bhh,
                       const float* __restrict__ Wih, const float* __restrict__ bout,
                       float* __restrict__ b0, float* __restrict__ bp)
{
    int r = blockIdx.x * 256 + threadIdx.x;
    if (r >= 8192) return;
    float s = bih[r] + bhh[r];
    float a = 0.f;
    for (int d = 0; d < 128; ++d) a += Wih[(size_t)r * 128 + d] * bout[d];
    b0[r] = s;        // step-0 bias
    bp[r] = s + a;    // recurrent bias (absorbs W_ih @ b_out)
}

// ---------------------------------------------------------------------------

extern "C" void kernel_launch(void* const* d_in, const int* in_sizes, int n_in,
                              void* d_out, int out_size, void* d_ws, size_t ws_size,
                              hipStream_t stream)
{
    const float* tgt  = (const float*)d_in[0];
    const float* Wih  = (const float*)d_in[1];
    const float* Whh  = (const float*)d_in[2];
    const float* bih  = (const float*)d_in[3];
    const float* bhh  = (const float*)d_in[4];
    const float* Wout = (const float*)d_in[5];
    const float* bout = (const float*)d_in[6];
    float* out = (float*)d_out;

    char* ws = (char*)d_ws;
    size_t off = 0;
    auto alloc = [&](size_t bytes) -> void* {
        void* p = ws + off;
        off += (bytes + 255) & ~(size_t)255;
        return p;
    };
    f16*   Wc     = (f16*)alloc((size_t)8192 * 2048 * 2);  // W_hh + W_ih*W_out
    f16*   Wih16  = (f16*)alloc((size_t)8192 * 128 * 2);
    f16*   Wout16 = (f16*)alloc((size_t)128 * 2048 * 2);
    f16*   WoutT  = (f16*)alloc((size_t)2048 * 128 * 2);
    f16*   x0     = (f16*)alloc((size_t)512 * 128 * 2);
    float* b0     = (float*)alloc(8192 * 4);
    float* bp     = (float*)alloc(8192 * 4);
    float* Cst    = (float*)alloc((size_t)512 * 2048 * 4);

    const size_t slotsz = (size_t)512 * 2048;  // elements per h snapshot
    int depth = 0;
    const int cands[7] = {128, 64, 32, 16, 8, 4, 2};
    for (int i = 0; i < 7; ++i)
        if (off + (size_t)cands[i] * slotsz * 2 <= ws_size) { depth = cands[i]; break; }
    if (depth == 0) return;
    f16* Hbuf = (f16*)alloc((size_t)depth * slotsz * 2);

    hipMemsetAsync(Cst, 0, (size_t)512 * 2048 * 4, stream);
    k_cast<<<dim3(4096), dim3(256), 0, stream>>>(Wih, Wih16, 1048576);
    k_cast<<<dim3(1024), dim3(256), 0, stream>>>(Wout, Wout16, 262144);
    k_tr  <<<dim3(32, 2), dim3(256), 0, stream>>>(Wout, WoutT);
    k_x0  <<<dim3(256), dim3(256), 0, stream>>>(tgt, x0);
    k_bias<<<dim3(32), dim3(256), 0, stream>>>(bih, bhh, Wih, bout, b0, bp);
    k_wcomb2<<<dim3(16, 64), dim3(256), 0, stream>>>(Wih16, WoutT, Whh, Wc);

    // step 0: gates = x0 @ W_ih^T + (b_ih+b_hh)  -> h^1 in slot 0
    k_step<<<dim3(256), dim3(256), 0, stream>>>(x0, 128, 128, Wih16, 128, b0, Cst, Hbuf);
    // steps 1..127: gates = h @ W'^T + b'
    for (int s = 1; s < 128; ++s) {
        if ((s % depth) == 0)
            k_out<<<dim3(depth * 4), dim3(256), 0, stream>>>(Hbuf, Wout16, bout, out, s - depth);
        k_step<<<dim3(256), dim3(256), 0, stream>>>(
            Hbuf + (size_t)((s - 1) % depth) * slotsz, 2048, 2048, Wc, 2048, bp,
            Cst, Hbuf + (size_t)(s % depth) * slotsz);
    }
    k_out<<<dim3(depth * 4), dim3(256), 0, stream>>>(Hbuf, Wout16, bout, out, 128 - depth);
}